// Round 8
// baseline (208.404 us; speedup 1.0000x reference)
//
#include <hip/hip_runtime.h>
#include <hip/hip_bf16.h>

typedef __bf16 bf16x8 __attribute__((ext_vector_type(8)));
typedef float f32x4 __attribute__((ext_vector_type(4)));
typedef unsigned short us;

__device__ __forceinline__ us f2bf(float f) {
  unsigned int u = __float_as_uint(f);
  u += 0x7fffu + ((u >> 16) & 1u);
  return (us)(u >> 16);
}

__device__ __forceinline__ unsigned int pack2(float lo, float hi) {
  __hip_bfloat162 h = __float22bfloat162_rn(float2{lo, hi});
  return *(unsigned int*)&h;
}

__device__ __forceinline__ void load_lds16(const void* g, void* l) {
  __builtin_amdgcn_global_load_lds(
      (const __attribute__((address_space(1))) unsigned int*)g,
      (__attribute__((address_space(3))) unsigned int*)l, 16, 0, 0);
}

// ---------------- elementwise f32 -> bf16 ----------------
__global__ void cvt_x(const float* __restrict__ in, us* __restrict__ out) {
  size_t i = ((size_t)blockIdx.x * 256 + threadIdx.x) * 4;
  float4 v = *(const float4*)(in + i);
  ushort4 o;
  o.x = f2bf(v.x); o.y = f2bf(v.y); o.z = f2bf(v.z); o.w = f2bf(v.w);
  *(ushort4*)(out + i) = o;
}

// ---------------- transpose f32 [R][C] -> bf16 [C][R] ----------------
__global__ void tr_w(const float* __restrict__ in, us* __restrict__ out,
                     int ldin, int ldout) {
  __shared__ float tile[32][33];
  const int c0 = blockIdx.x * 32, r0 = blockIdx.y * 32;
  const int tx = threadIdx.x, ty = threadIdx.y;
#pragma unroll
  for (int j = 0; j < 4; ++j)
    tile[ty + j * 8][tx] = in[(size_t)(r0 + ty + j * 8) * ldin + c0 + tx];
  __syncthreads();
#pragma unroll
  for (int j = 0; j < 4; ++j)
    out[(size_t)(c0 + ty + j * 8) * ldout + r0 + tx] = f2bf(tile[tx][ty + j * 8]);
}

// ---------------- V slice of QKV -> VT [b*4+kv][128][2048] ----------------
__global__ void tr_v(const us* __restrict__ QKV, us* __restrict__ VT) {
  __shared__ us tile[32][33];
  const int z = blockIdx.z, b = z >> 2, kvh = z & 3;
  const us* in = QKV + (size_t)(b * 2048) * 3072 + 2560 + kvh * 128;
  us* out = VT + (size_t)z * 128 * 2048;
  const int c0 = blockIdx.x * 32, r0 = blockIdx.y * 32;
  const int tx = threadIdx.x, ty = threadIdx.y;
#pragma unroll
  for (int j = 0; j < 4; ++j)
    tile[ty + j * 8][tx] = in[(size_t)(r0 + ty + j * 8) * 3072 + c0 + tx];
  __syncthreads();
#pragma unroll
  for (int j = 0; j < 4; ++j)
    out[(size_t)(c0 + ty + j * 8) * 2048 + r0 + tx] = tile[tx][ty + j * 8];
}

// ============ bf16 GEMM 256x256, 8-phase schedule (T2+T3+T4+T5 faithful port) ============
// 512 thr = 8 waves (2M x 4N), per-wave C = 128x64. BK=64. LDS: A,B x 2buf x 2 halves [128][64].
// Phases per K-tile = C-quadrants (fq,nq) in order (0,0)(0,1)(1,0)(1,1):
//   reads P1{8A+4B} P2{4B} P3{8A} P4{0}; 16 MFMA each.
// Stage sequence over 8 phases: A1(T+1) B1(T+1) B0(T+2) A0(T+2) B1(T+2) A1(T+2) B0(T+3) A0(T+3)
//   (each stage issued only after the barrier following the last read of the region it overwrites:
//    A-half reads end P3/P7, B-half reads end P2/P6).
// vmcnt(4) only at P4/P8: prologue 6 halves + p1..p4 => tile T+1 confirmed at P4, T+2 at P8.
// Tail: guarded stages tighten vmcnt to 0 (invariant preserved exactly).
template <int OUTF32>
__global__ __launch_bounds__(512, 2) void gemm8p(const us* __restrict__ A,
                                                 const us* __restrict__ B,
                                                 void* __restrict__ Cv,
                                                 int M, int N, int K) {
  __shared__ __attribute__((aligned(16))) us As[2][2][128 * 64];
  __shared__ __attribute__((aligned(16))) us Bs[2][2][128 * 64];
  const int tid = threadIdx.x;
  const int lane = tid & 63;
  const int cl = lane & 15, rg = lane >> 4;
  const int wave = tid >> 6;
  const int wm = wave >> 2, wn = wave & 3;
  const int bm = blockIdx.y, bn = blockIdx.x;
  const int NK = K >> 6;
  const int rowA = bm * 256, rowB = bn * 256;

  f32x4 acc[8][4] = {};

  auto stA = [&](int bf, int h, int kt) {
#pragma unroll
    for (int i = 0; i < 2; ++i) {
      const int L = i * 512 + tid;
      const int r = L >> 3, c = (L & 7) ^ (r & 7);
      load_lds16(A + (size_t)(rowA + h * 128 + r) * K + kt * 64 + c * 8,
                 &As[bf][h][(i * 512 + (tid & ~63)) * 8]);
    }
  };
  auto stB = [&](int bf, int h, int kt) {
#pragma unroll
    for (int i = 0; i < 2; ++i) {
      const int L = i * 512 + tid;
      const int r = L >> 3, c = (L & 7) ^ (r & 7);
      load_lds16(B + (size_t)(rowB + h * 128 + r) * K + kt * 64 + c * 8,
                 &Bs[bf][h][(i * 512 + (tid & ~63)) * 8]);
    }
  };

  const int pxor = cl & 7;
  bf16x8 aA[4][2], bA[2][2], bB[2][2];

  auto rdA = [&](int bf, int fq) {
#pragma unroll
    for (int f = 0; f < 4; ++f) {
      const int r = fq * 64 + f * 16 + cl;
#pragma unroll
      for (int ks = 0; ks < 2; ++ks)
        aA[f][ks] = *(const bf16x8*)(&As[bf][wm][(r * 8 + ((ks * 4 + rg) ^ pxor)) * 8]);
    }
  };
  auto rdB = [&](bf16x8 (&b)[2][2], int bf, int nq) {
#pragma unroll
    for (int j = 0; j < 2; ++j) {
      const int r = (wn & 1) * 64 + (nq * 2 + j) * 16 + cl;
#pragma unroll
      for (int ks = 0; ks < 2; ++ks)
        b[j][ks] = *(const bf16x8*)(&Bs[bf][wn >> 1][(r * 8 + ((ks * 4 + rg) ^ pxor)) * 8]);
    }
  };
  auto mmQ = [&](bf16x8 (&b)[2][2], int fq, int nq) {
    __builtin_amdgcn_s_setprio(1);
#pragma unroll
    for (int f = 0; f < 4; ++f)
#pragma unroll
      for (int j = 0; j < 2; ++j)
#pragma unroll
        for (int ks = 0; ks < 2; ++ks)
          acc[fq * 4 + f][nq * 2 + j] = __builtin_amdgcn_mfma_f32_16x16x32_bf16(
              aA[f][ks], b[j][ks], acc[fq * 4 + f][nq * 2 + j], 0, 0, 0);
    __builtin_amdgcn_s_setprio(0);
  };

#define BAR __builtin_amdgcn_s_barrier()
#define LGK0 asm volatile("s_waitcnt lgkmcnt(0)" ::: "memory")
#define VM4 asm volatile("s_waitcnt vmcnt(4)" ::: "memory")
#define VM0 asm volatile("s_waitcnt vmcnt(0)" ::: "memory")

  // prologue: tile0 all halves + B0,A0 of tile1; wait tile0 (keep last 2 ops = 4 loads in flight)
  stA(0, 0, 0); stB(0, 0, 0); stA(0, 1, 0); stB(0, 1, 0);
  stB(1, 0, 1); stA(1, 0, 1);
  VM4;
  BAR;

#pragma unroll 1
  for (int T = 0; T < NK; T += 2) {
    const bool s34 = (T + 2) < NK, s78 = (T + 3) < NK;

    // ---------- tile T (buf 0) ----------
    rdA(0, 0); rdB(bA, 0, 0);
    stA(1, 1, T + 1);
    asm volatile("s_waitcnt lgkmcnt(8)" ::: "memory");
    BAR; LGK0; mmQ(bA, 0, 0); BAR;

    rdB(bB, 0, 1);
    stB(1, 1, T + 1);
    BAR; LGK0; mmQ(bB, 0, 1); BAR;

    rdA(0, 1);
    if (s34) stB(0, 0, T + 2);
    BAR; LGK0; mmQ(bA, 1, 0); BAR;

    if (s34) stA(0, 0, T + 2);
    BAR; mmQ(bB, 1, 1);
    if (s34) { VM4; } else { VM0; }
    BAR;

    // ---------- tile T+1 (buf 1) ----------
    rdA(1, 0); rdB(bA, 1, 0);
    if (s34) stB(0, 1, T + 2);
    asm volatile("s_waitcnt lgkmcnt(8)" ::: "memory");
    BAR; LGK0; mmQ(bA, 0, 0); BAR;

    rdB(bB, 1, 1);
    if (s34) stA(0, 1, T + 2);
    BAR; LGK0; mmQ(bB, 0, 1); BAR;

    rdA(1, 1);
    if (s78) stB(1, 0, T + 3);
    BAR; LGK0; mmQ(bA, 1, 0); BAR;

    if (s78) stA(1, 0, T + 3);
    BAR; mmQ(bB, 1, 1);
    if (s78) { VM4; } else { VM0; }
    BAR;
  }
#undef BAR
#undef LGK0
#undef VM4
#undef VM0

#pragma unroll
  for (int f = 0; f < 8; ++f)
#pragma unroll
    for (int nf = 0; nf < 4; ++nf)
#pragma unroll
      for (int i = 0; i < 4; ++i) {
        const int row = bm * 256 + wm * 128 + f * 16 + rg * 4 + i;
        const int col = bn * 256 + wn * 64 + nf * 16 + cl;
        if (OUTF32)
          ((float*)Cv)[(size_t)row * N + col] = acc[f][nf][i];
        else
          ((us*)Cv)[(size_t)row * N + col] = f2bf(acc[f][nf][i]);
      }
}

// ---------------- bf16 GEMM 256x(64*NF) (kept for Wo): one barrier per K-tile ----------------
template <int NF, int OUTF32>
__global__ __launch_bounds__(512, 2) void gemm256(const us* __restrict__ A,
                                                  const us* __restrict__ B,
                                                  void* __restrict__ Cv, int M, int N, int K) {
  __shared__ __attribute__((aligned(16))) us Ah[2][2][256 * 32];
  __shared__ __attribute__((aligned(16))) us Bf[2][64 * NF * 64];
  const int tid = threadIdx.x;
  const int lane = tid & 63;
  const int cl = lane & 15, rg = lane >> 4;
  const int wave = tid >> 6;
  const int wm = wave >> 2, wn = wave & 3;
  const int bm = blockIdx.y, bn = blockIdx.x;
  const int NK = K >> 6;
  const int rowA = bm * 256, rowB = bn * (64 * NF);

  f32x4 acc[8][NF] = {};

  auto stage_A = [&](int bf, int h, int kt) {
#pragma unroll
    for (int i = 0; i < 2; ++i) {
      const int L = i * 512 + tid;
      const int r = L >> 2;
      const int c = (L & 3) ^ ((r >> 1) & 3);
      load_lds16(A + (size_t)(rowA + r) * K + kt * 64 + h * 32 + c * 8,
                 &Ah[bf][h][(size_t)(i * 512 + (tid & ~63)) * 8]);
    }
  };
  auto stage_B = [&](int bf, int kt) {
#pragma unroll
    for (int i = 0; i < NF; ++i) {
      const int L = i * 512 + tid;
      const int r = L >> 3;
      const int c = (L & 7) ^ (r & 7);
      load_lds16(B + (size_t)(rowB + r) * K + kt * 64 + c * 8,
                 &Bf[bf][(size_t)(i * 512 + (tid & ~63)) * 8]);
    }
  };

  stage_B(0, 0);
  stage_A(0, 0, 0);
  stage_A(0, 1, 0);
  __syncthreads();

  int buf = 0;
#pragma unroll 1
  for (int kt = 0; kt < NK; ++kt) {
    const bool nl = (kt + 1 < NK);
    if (nl) {
      stage_B(buf ^ 1, kt + 1);
      stage_A(buf ^ 1, 0, kt + 1);
      stage_A(buf ^ 1, 1, kt + 1);
    }
    {
      bf16x8 af[8], bfr[NF];
#pragma unroll
      for (int f = 0; f < 8; ++f) {
        const int r = 128 * wm + 16 * f + cl;
        af[f] = *(const bf16x8*)(&Ah[buf][0][(r * 4 + (rg ^ ((r >> 1) & 3))) * 8]);
      }
#pragma unroll
      for (int nf = 0; nf < NF; ++nf) {
        const int r = 16 * NF * wn + 16 * nf + cl;
        bfr[nf] = *(const bf16x8*)(&Bf[buf][(r * 8 + (rg ^ (r & 7))) * 8]);
      }
      __builtin_amdgcn_s_setprio(1);
#pragma unroll
      for (int f = 0; f < 8; ++f)
#pragma unroll
        for (int nf = 0; nf < NF; ++nf)
          acc[f][nf] = __builtin_amdgcn_mfma_f32_16x16x32_bf16(af[f], bfr[nf], acc[f][nf], 0, 0, 0);
      __builtin_amdgcn_s_setprio(0);
    }
    {
      bf16x8 af[8], bfr[NF];
#pragma unroll
      for (int f = 0; f < 8; ++f) {
        const int r = 128 * wm + 16 * f + cl;
        af[f] = *(const bf16x8*)(&Ah[buf][1][(r * 4 + (rg ^ ((r >> 1) & 3))) * 8]);
      }
#pragma unroll
      for (int nf = 0; nf < NF; ++nf) {
        const int r = 16 * NF * wn + 16 * nf + cl;
        bfr[nf] = *(const bf16x8*)(&Bf[buf][(r * 8 + ((4 + rg) ^ (r & 7))) * 8]);
      }
      __builtin_amdgcn_s_setprio(1);
#pragma unroll
      for (int f = 0; f < 8; ++f)
#pragma unroll
        for (int nf = 0; nf < NF; ++nf)
          acc[f][nf] = __builtin_amdgcn_mfma_f32_16x16x32_bf16(af[f], bfr[nf], acc[f][nf], 0, 0, 0);
      __builtin_amdgcn_s_setprio(0);
    }
    __syncthreads();
    buf ^= 1;
  }

#pragma unroll
  for (int f = 0; f < 8; ++f)
#pragma unroll
    for (int nf = 0; nf < NF; ++nf)
#pragma unroll
      for (int i = 0; i < 4; ++i) {
        const int row = bm * 256 + wm * 128 + f * 16 + rg * 4 + i;
        const int col = bn * 64 * NF + wn * 16 * NF + nf * 16 + cl;
        if (OUTF32)
          ((float*)Cv)[(size_t)row * N + col] = acc[f][nf][i];
        else
          ((us*)Cv)[(size_t)row * N + col] = f2bf(acc[f][nf][i]);
      }
}

// ---------------- causal GQA flash attention (round-5 version) ----------------
__global__ __launch_bounds__(256, 2) void attn(const us* __restrict__ QKV,
                                               const us* __restrict__ VT,
                                               us* __restrict__ O) {
  __shared__ __attribute__((aligned(16))) us Ks[2][64 * 128];
  __shared__ __attribute__((aligned(16))) us VTs[2][128 * 64];
  const int T = 2048, LD = 3072, D = 2048;
  const int jp = blockIdx.x, h = blockIdx.y, b = blockIdx.z;
  const int kvh = h >> 2;
  const int tid = threadIdx.x, lane = tid & 63, wave = tid >> 6;
  const int cl = lane & 15, rg = lane >> 4;
  const bool abit = (lane & 16) != 0, bbit = (lane & 32) != 0;
  const bool ab = abit != bbit;
  const us* Kbase = QKV + (size_t)b * T * LD + 2048 + kvh * 128;
  const us* Vbase = VT + (size_t)(b * 4 + kvh) * 128 * T;

  auto stage = [&](int sb, int k0) {
#pragma unroll
    for (int i = 0; i < 4; ++i) {
      const int Ls = i * 256 + tid;
      const int r = Ls >> 4, s = Ls & 15, c = s ^ (r & 7);
      load_lds16(Kbase + (size_t)(k0 + r) * LD + c * 8,
                 &Ks[sb][(i * 256 + (tid & 0xC0)) * 8]);
    }
#pragma unroll
    for (int i = 0; i < 4; ++i) {
      const int Ls = i * 256 + tid;
      const int r = Ls >> 3, s = Ls & 7, c = s ^ (r & 7);
      load_lds16(Vbase + (size_t)r * T + k0 + c * 8,
                 &VTs[sb][(i * 256 + (tid & 0xC0)) * 8]);
    }
  };

  const float scale = 0.08838834764831845f;  // 1/sqrt(128)

#pragma unroll 1
  for (int pass = 0; pass < 2; ++pass) {
    const int jt = pass ? (31 - jp) : jp;
    const int q0 = jt * 64;
    const int nkt = jt + 1;
    const int qrow = q0 + wave * 16 + cl;

    const us* Qp = QKV + (size_t)(b * T + qrow) * LD + h * 128;
    bf16x8 qf[4];
#pragma unroll
    for (int ks = 0; ks < 4; ++ks) qf[ks] = *(const bf16x8*)(Qp + ks * 32 + rg * 8);

    f32x4 o[8] = {};
    float m = -1e30f, l = 0.f;
    int buf = 0;

    stage(0, 0);
    __syncthreads();

#pragma unroll 1
    for (int kt = 0; kt < nkt; ++kt) {
      if (kt + 1 < nkt) stage(buf ^ 1, (kt + 1) * 64);

      f32x4 sa[4] = {};
      __builtin_amdgcn_s_setprio(1);
#pragma unroll
      for (int ks = 0; ks < 4; ++ks) {
#pragma unroll
        for (int n = 0; n < 4; ++n) {
          const int row = n * 16 + cl;
          const int p = (ks * 4 + rg) ^ (row & 7);
          const bf16x8 kf = *(const bf16x8*)(&Ks[buf][row * 128 + p * 8]);
          sa[n] = __builtin_amdgcn_mfma_f32_16x16x32_bf16(kf, qf[ks], sa[n], 0, 0, 0);
        }
      }
      __builtin_amdgcn_s_setprio(0);

      const int k0 = kt * 64;
      float p[4][4];
      float pmax = -1e30f;
      if (kt == jt) {
#pragma unroll
        for (int n = 0; n < 4; ++n)
#pragma unroll
          for (int i = 0; i < 4; ++i) {
            const int kg = k0 + n * 16 + rg * 4 + i;
            p[n][i] = (kg > qrow) ? -1e30f : sa[n][i] * scale;
            pmax = fmaxf(pmax, p[n][i]);
          }
      } else {
#pragma unroll
        for (int n = 0; n < 4; ++n)
#pragma unroll
          for (int i = 0; i < 4; ++i) {
            p[n][i] = sa[n][i] * scale;
            pmax = fmaxf(pmax, p[n][i]);
          }
      }
      pmax = fmaxf(pmax, __shfl_xor(pmax, 16));
      pmax = fmaxf(pmax, __shfl_xor(pmax, 32));

      if (!__all(pmax <= m + 8.f)) {  // T13 defer-max
        const float mnew = fmaxf(m, pmax);
        const float alpha = __expf(m - mnew);
        m = mnew;
        l *= alpha;
#pragma unroll
        for (int n2 = 0; n2 < 8; ++n2) o[n2] *= alpha;
      }

      float rs = 0.f;
#pragma unroll
      for (int n = 0; n < 4; ++n)
#pragma unroll
        for (int i = 0; i < 4; ++i) {
          p[n][i] = __expf(p[n][i] - m);
          rs += p[n][i];
        }
      rs += __shfl_xor(rs, 16);
      rs += __shfl_xor(rs, 32);
      l += rs;

      unsigned int F[2][4];
#pragma unroll
      for (int ks2 = 0; ks2 < 2; ++ks2) {
        const unsigned int pk00 = pack2(p[2 * ks2][0], p[2 * ks2][1]);
        const unsigned int pk01 = pack2(p[2 * ks2][2], p[2 * ks2][3]);
        const unsigned int pk10 = pack2(p[2 * ks2 + 1][0], p[2 * ks2 + 1][1]);
        const unsigned int pk11 = pack2(p[2 * ks2 + 1][2], p[2 * ks2 + 1][3]);
        const unsigned int s0 = bbit ? pk00 : pk10;
        const unsigned int s1 = bbit ? pk01 : pk11;
        const unsigned int r0 = (unsigned int)__shfl_xor((int)s0, 32);
        const unsigned int r1 = (unsigned int)__shfl_xor((int)s1, 32);
        const unsigned int gk0 = bbit ? pk10 : pk00;
        const unsigned int gk1 = bbit ? pk11 : pk01;
        const unsigned int t0 = ab ? gk0 : r0;
        const unsigned int t1 = ab ? gk1 : r1;
        const unsigned int u0 = (unsigned int)__shfl_xor((int)t0, 16);
        const unsigned int u1 = (unsigned int)__shfl_xor((int)t1, 16);
        const unsigned int k20 = ab ? r0 : gk0;
        const unsigned int k21 = ab ? r1 : gk1;
        F[ks2][0] = abit ? u0 : k20;
        F[ks2][1] = abit ? u1 : k21;
        F[ks2][2] = abit ? k20 : u0;
        F[ks2][3] = abit ? k21 : u1;
      }

      __builtin_amdgcn_s_setprio(1);
#pragma unroll
      for (int ks2 = 0; ks2 < 2; ++ks2) {
        uint4 fu = make_uint4(F[ks2][0], F[ks2][1], F[ks2][2], F[ks2][3]);
        const bf16x8 pf = *(const bf16x8*)&fu;
#pragma unroll
        for (int n2 = 0; n2 < 8; ++n2) {
          const int dr = n2 * 16 + cl;
          const int p2 = (ks2 * 4 + rg) ^ (dr & 7);
          const bf16x8 vf = *(const bf16x8*)(&VTs[buf][dr * 64 + p2 * 8]);
          o[n2] = __builtin_amdgcn_mfma_f32_16x16x32_bf16(vf, pf, o[n2], 0, 0, 0);
        }
      }
      __builtin_amdgcn_s_setprio(0);

      __syncthreads();
      buf ^= 1;
    }

    const float rl = __builtin_amdgcn_rcpf(l);
#pragma unroll
    for (int n2 = 0; n2 < 8; ++n2) {
      ushort4 ov;
      ov.x = f2bf(o[n2][0] * rl);
      ov.y = f2bf(o[n2][1] * rl);
      ov.z = f2bf(o[n2][2] * rl);
      ov.w = f2bf(o[n2][3] * rl);
      *(ushort4*)(O + (size_t)(b * T + qrow) * D + h * 128 + n2 * 16 + rg * 4) = ov;
    }
  }
}

extern "C" void kernel_launch(void* const* d_in, const int* in_sizes, int n_in,
                              void* d_out, int out_size, void* d_ws, size_t ws_size,
                              hipStream_t stream) {
  const float* x = (const float*)d_in[0];
  const float* Wq = (const float*)d_in[1];
  const float* Wk = (const float*)d_in[2];
  const float* Wv = (const float*)d_in[3];
  const float* Wo = (const float*)d_in[4];
  float* out = (float*)d_out;

  char* ws = (char*)d_ws;
  us* xb    = (us*)(ws);                 // x bf16, later attn O
  us* WqkvT = (us*)(ws + 16777216);      // [3072][2048]
  us* WoT   = (us*)(ws + 29360128);      // [2048][2048]
  us* QKV   = (us*)(ws + 37748736);      // [4096][3072]
  us* VTb   = (us*)(ws + 62914560);      // [8][128][2048]

  cvt_x<<<dim3(8192), dim3(256), 0, stream>>>(x, xb);
  tr_w<<<dim3(64, 64), dim3(32, 8), 0, stream>>>(Wq, WqkvT, 2048, 2048);
  tr_w<<<dim3(16, 64), dim3(32, 8), 0, stream>>>(Wk, WqkvT + (size_t)2048 * 2048, 512, 2048);
  tr_w<<<dim3(16, 64), dim3(32, 8), 0, stream>>>(Wv, WqkvT + (size_t)2560 * 2048, 512, 2048);
  tr_w<<<dim3(64, 64), dim3(32, 8), 0, stream>>>(Wo, WoT, 2048, 2048);

  gemm8p<0><<<dim3(12, 16), dim3(512), 0, stream>>>(xb, WqkvT, QKV, 4096, 3072, 2048);
  tr_v<<<dim3(4, 64, 8), dim3(32, 8), 0, stream>>>(QKV, VTb);
  attn<<<dim3(16, 16, 2), dim3(256), 0, stream>>>(QKV, VTb, xb);
  gemm256<2, 1><<<dim3(16, 16), dim3(512), 0, stream>>>(xb, WoT, out, 4096, 2048, 2048);
}